// Round 3
// baseline (345443.042 us; speedup 1.0000x reference)
//
#include <hip/hip_runtime.h>
#include <stdint.h>

#define HID 1024
#define NLAYERS 8
#define NLET 100
#define T_TOTAL 4096

typedef uint32_t u32x4 __attribute__((ext_vector_type(4)));

// ---------- helpers ----------
__device__ __forceinline__ uint32_t f2bf(float f) {
    uint32_t u = __float_as_uint(f);
    return (u + 0x7FFFu + ((u >> 16) & 1u)) >> 16;
}
__device__ __forceinline__ float bflo(uint32_t p) { return __uint_as_float(p << 16); }
__device__ __forceinline__ float bfhi(uint32_t p) { return __uint_as_float(p & 0xFFFF0000u); }
__device__ __forceinline__ float sigm(float x) { return 1.0f / (1.0f + __expf(-x)); }
__device__ __forceinline__ float tanh_f(float x) {
    float xx = fminf(fmaxf(x, -15.0f), 15.0f);
    float e = __expf(2.0f * xx);
    return (e - 1.0f) / (e + 1.0f);
}

// device-coherent (bypass L1+L2) ops
__device__ __forceinline__ void store_coh_x4(void* p, u32x4 d) {
    asm volatile("global_store_dwordx4 %0, %1, off sc0 sc1" ::"v"(p), "v"(d) : "memory");
}
__device__ __forceinline__ void store_coh_b32(void* p, uint32_t d) {
    asm volatile("global_store_dword %0, %1, off sc0 sc1" ::"v"(p), "v"(d) : "memory");
}
__device__ __forceinline__ u32x4 load_coh_x4(const void* p) {
    u32x4 a;
    asm volatile("global_load_dwordx4 %0, %1, off sc0 sc1\n\ts_waitcnt vmcnt(0)"
                 : "=v"(a)
                 : "v"(p)
                 : "memory");
    return a;
}
__device__ __forceinline__ void load_coh_4x4(const void* p0, const void* p1, const void* p2,
                                             const void* p3, u32x4& a, u32x4& b, u32x4& c,
                                             u32x4& d) {
    asm volatile(
        "global_load_dwordx4 %0, %4, off sc0 sc1\n\t"
        "global_load_dwordx4 %1, %5, off sc0 sc1\n\t"
        "global_load_dwordx4 %2, %6, off sc0 sc1\n\t"
        "global_load_dwordx4 %3, %7, off sc0 sc1\n\t"
        "s_waitcnt vmcnt(0)"
        : "=v"(a), "=v"(b), "=v"(c), "=v"(d)
        : "v"(p0), "v"(p1), "v"(p2), "v"(p3)
        : "memory");
}

// ---------- kernel 1: persistent stacked-LSTM scan ----------
// 256 blocks x 512 threads (8 waves), 1 block/CU (VGPR-forced). Block b owns units
// {4b..4b+3}. Wave w: unit u=w&3, layer-half=w>>2 (layers half*4..half*4+3).
// Weights register-resident bf16 (128 wh + 16 wx + 16 bias regs/lane, no spill).
// Mailbox (d_ws): data float4[2][256] @0 (8KB); tags u32[2][4][256] @8192 (8KB).
// Protocol per step s: wave1 lane0 stores data chunk (sc0 sc1), vmcnt(0) release,
// lanes0-3 store tag s to 4 replicas. Wave0 polls replica (b&3): 64 lanes x 4 tags
// (one dwordx4 each) until all==s, then fetches all 256 chunks (4 dwordx4/lane,
// one vmcnt) and stages into LDS. Two barriers/step. Parity double-buffer; skew<=2
// steps so tag==s test is race-free; data overwrite for s+2 provably ordered after
// every consumer's data load of s.
__global__ void __launch_bounds__(512, 2)
lstm_persistent(const float* __restrict__ website, const float* __restrict__ payload,
                const float* __restrict__ W_ih, const float* __restrict__ W_hh,
                const float* __restrict__ b_ih, const float* __restrict__ b_hh,
                char* mbox, float* c_out) {
    __shared__ __align__(16) float h_lds[HID];
    __shared__ float h_new[4];
    __shared__ float c_lds[4];

    const int tid = threadIdx.x;  // 0..511
    const int b = blockIdx.x;     // 0..255
    const int w = tid >> 6;       // wave 0..7
    const int lane = tid & 63;
    const int u = w & 3;          // unit within block
    const int half = w >> 2;      // 0: layers 0-3, 1: layers 4-7
    const int k = b * 4 + u;      // global hidden unit

    u32x4* dataP = (u32x4*)mbox;                // [par*256 + producer]
    uint32_t* tagP = (uint32_t*)(mbox + 8192);  // [(par*4 + rep)*256 + producer]

    // ---- one-time: pack this wave's weights into registers as bf16 pairs ----
    uint32_t wh[4][4][8];  // [local layer ll][gate][pair p] -> cols (2L+128p, +1)
    uint32_t wx[4][4];
    float bias[4][4];
#pragma unroll
    for (int ll = 0; ll < 4; ++ll) {
        const int l = half * 4 + ll;
#pragma unroll
        for (int g = 0; g < 4; ++g) {
            const int row = 1024 * g + k;
            const float* src = W_hh + ((size_t)(l * 4096 + row)) * 1024;
#pragma unroll
            for (int p = 0; p < 8; ++p) {
                const int c0 = 2 * lane + 128 * p;
                wh[ll][g][p] = f2bf(src[c0]) | (f2bf(src[c0 + 1]) << 16);
            }
            if (lane < 50) {
                const float* sx = W_ih + ((size_t)(l * 4096 + row)) * NLET + 2 * lane;
                wx[ll][g] = f2bf(sx[0]) | (f2bf(sx[1]) << 16);
            } else {
                wx[ll][g] = 0u;
            }
            bias[ll][g] = b_ih[l * 4096 + row] + b_hh[l * 4096 + row];
        }
    }

    if (tid < 256) ((float4*)h_lds)[tid] = make_float4(0.f, 0.f, 0.f, 0.f);
    if (tid < 4) c_lds[tid] = 0.0f;
    __syncthreads();

    for (int t = 0; t < T_TOTAL; ++t) {
        float x0 = 0.f, x1 = 0.f;
        if (lane < 50) {
            const float* xp = (t < 2048) ? (website + (size_t)t * NLET)
                                         : (payload + (size_t)(t - 2048) * NLET);
            x0 = xp[2 * lane];
            x1 = xp[2 * lane + 1];
        }
#pragma unroll
        for (int l = 0; l < NLAYERS; ++l) {
            const int s = t * NLAYERS + l + 1;  // step being produced
            const int par = s & 1;

            if ((l >> 2) == half) {
                const int ll = l & 3;
                float2 hv[8];
#pragma unroll
                for (int p = 0; p < 8; ++p) hv[p] = *(const float2*)&h_lds[2 * lane + 128 * p];
                float acc0 = 0.f, acc1 = 0.f, acc2 = 0.f, acc3 = 0.f;
#pragma unroll
                for (int p = 0; p < 8; ++p) {
                    const float hA = hv[p].x, hB = hv[p].y;
                    uint32_t ww;
                    ww = wh[ll][0][p]; acc0 = fmaf(bflo(ww), hA, acc0); acc0 = fmaf(bfhi(ww), hB, acc0);
                    ww = wh[ll][1][p]; acc1 = fmaf(bflo(ww), hA, acc1); acc1 = fmaf(bfhi(ww), hB, acc1);
                    ww = wh[ll][2][p]; acc2 = fmaf(bflo(ww), hA, acc2); acc2 = fmaf(bfhi(ww), hB, acc2);
                    ww = wh[ll][3][p]; acc3 = fmaf(bflo(ww), hA, acc3); acc3 = fmaf(bfhi(ww), hB, acc3);
                }
                {
                    uint32_t ww;
                    ww = wx[ll][0]; acc0 = fmaf(bflo(ww), x0, acc0); acc0 = fmaf(bfhi(ww), x1, acc0);
                    ww = wx[ll][1]; acc1 = fmaf(bflo(ww), x0, acc1); acc1 = fmaf(bfhi(ww), x1, acc1);
                    ww = wx[ll][2]; acc2 = fmaf(bflo(ww), x0, acc2); acc2 = fmaf(bfhi(ww), x1, acc2);
                    ww = wx[ll][3]; acc3 = fmaf(bflo(ww), x0, acc3); acc3 = fmaf(bfhi(ww), x1, acc3);
                }
#pragma unroll
                for (int mm = 32; mm > 0; mm >>= 1) {
                    acc0 += __shfl_xor(acc0, mm, 64);
                    acc1 += __shfl_xor(acc1, mm, 64);
                    acc2 += __shfl_xor(acc2, mm, 64);
                    acc3 += __shfl_xor(acc3, mm, 64);
                }
                const float gi = sigm(acc0 + bias[ll][0]);
                const float gf = sigm(acc1 + bias[ll][1]);
                const float gg = tanh_f(acc2 + bias[ll][2]);
                const float go = sigm(acc3 + bias[ll][3]);
                const float cn = fmaf(gf, c_lds[u], gi * gg);
                const float hn = go * tanh_f(cn);
                if (lane == 0) {
                    c_lds[u] = cn;
                    h_new[u] = hn;
                }
            }
            __syncthreads();  // h_new/c ready; everyone done with h_lds

            if (w == 1) {
                // ---- publish: 16B data chunk, release, 4 tag replicas ----
                if (lane == 0) {
                    u32x4 d;
                    d.x = __float_as_uint(h_new[0]);
                    d.y = __float_as_uint(h_new[1]);
                    d.z = __float_as_uint(h_new[2]);
                    d.w = __float_as_uint(h_new[3]);
                    store_coh_x4(&dataP[par * 256 + b], d);
                }
                asm volatile("s_waitcnt vmcnt(0)" ::: "memory");  // release: data visible
                if (lane < 4) store_coh_b32(&tagP[(par * 4 + lane) * 256 + b], (uint32_t)s);
            }
            if (w == 0) {
                // ---- poll tag replica (b&3): 4 tags per lane ----
                const uint32_t* tp = &tagP[(par * 4 + (b & 3)) * 256 + lane * 4];
                const uint32_t su = (uint32_t)s;
                for (;;) {
                    u32x4 tg = load_coh_x4(tp);
                    const bool ok = (tg.x == su) & (tg.y == su) & (tg.z == su) & (tg.w == su);
                    if (__all(ok)) break;
                }
                // ---- fetch all 256 chunks (4 per lane, one vmcnt) and stage ----
                const u32x4* dp = &dataP[par * 256];
                u32x4 a0, a1, a2, a3;
                load_coh_4x4(dp + lane, dp + lane + 64, dp + lane + 128, dp + lane + 192, a0, a1,
                             a2, a3);
                u32x4* hq = (u32x4*)h_lds;
                hq[lane] = a0;
                hq[lane + 64] = a1;
                hq[lane + 128] = a2;
                hq[lane + 192] = a3;
            }
            __syncthreads();  // h_lds now holds h(s)
        }
    }
    if (tid < 4) c_out[b * 4 + tid] = c_lds[tid];
}

// ---------- kernel 2: head — out = sigmoid(W_out @ (W_lin@c + b_lin) + b_out) ----------
__global__ void head_kernel(const float* __restrict__ c_out, const float* __restrict__ W_lin,
                            const float* __restrict__ b_lin, const float* __restrict__ W_out,
                            const float* __restrict__ b_out, float* out) {
    const int lane = threadIdx.x;  // 64 threads, one wave
    float cv[16];
    const float4* cp = (const float4*)(c_out + lane * 16);
#pragma unroll
    for (int q = 0; q < 4; ++q) {
        float4 v = cp[q];
        cv[4 * q + 0] = v.x;
        cv[4 * q + 1] = v.y;
        cv[4 * q + 2] = v.z;
        cv[4 * q + 3] = v.w;
    }
    float fsum = 0.f;
#pragma unroll
    for (int i = 0; i < 16; ++i) {
        const float* wr = W_lin + (size_t)i * HID + lane * 16;
        float a = 0.f;
#pragma unroll
        for (int m = 0; m < 16; ++m) a = fmaf(wr[m], cv[m], a);
#pragma unroll
        for (int mm = 32; mm > 0; mm >>= 1) a += __shfl_xor(a, mm, 64);
        fsum = fmaf(W_out[i], a + b_lin[i], fsum);
    }
    if (lane == 0) out[0] = sigm(fsum + b_out[0]);
}

extern "C" void kernel_launch(void* const* d_in, const int* in_sizes, int n_in, void* d_out,
                              int out_size, void* d_ws, size_t ws_size, hipStream_t stream) {
    (void)in_sizes; (void)n_in; (void)out_size; (void)ws_size;
    const float* website = (const float*)d_in[0];
    const float* payload = (const float*)d_in[1];
    const float* W_ih = (const float*)d_in[2];
    const float* W_hh = (const float*)d_in[3];
    const float* b_ih = (const float*)d_in[4];
    const float* b_hh = (const float*)d_in[5];
    const float* W_lin = (const float*)d_in[6];
    const float* b_lin = (const float*)d_in[7];
    const float* W_out = (const float*)d_in[8];
    const float* b_out = (const float*)d_in[9];

    char* mbox = (char*)d_ws;                      // 16 KB: data(8K) + tags(8K)
    float* c_out = (float*)((char*)d_ws + 16384);  // 4 KB

    hipMemsetAsync(mbox, 0, 16384, stream);  // zero tags (step ids start at 1)
    lstm_persistent<<<256, 512, 0, stream>>>(website, payload, W_ih, W_hh, b_ih, b_hh, mbox,
                                             c_out);
    head_kernel<<<1, 64, 0, stream>>>(c_out, W_lin, b_lin, W_out, b_out, (float*)d_out);
}